// Round 2
// baseline (230.834 us; speedup 1.0000x reference)
//
#include <hip/hip_runtime.h>

typedef unsigned short u16;
typedef unsigned int u32;
typedef __attribute__((ext_vector_type(4))) float f32x4;
typedef __attribute__((ext_vector_type(4))) u16 u16x4;
typedef __attribute__((ext_vector_type(8))) u16 u16x8;
typedef __attribute__((ext_vector_type(8))) __bf16 bf16x8;

#define DEV static __device__ __forceinline__

DEV u16 f2b(float f) {
  u32 u = __builtin_bit_cast(u32, f);
  u32 r = (u + 0x7fffu + ((u >> 16) & 1u)) >> 16;
  return (u16)r;
}

DEV bf16x8 mk8(u16x4 lo, u16x4 hi) {
  u16x8 v = __builtin_shufflevector(lo, hi, 0, 1, 2, 3, 4, 5, 6, 7);
  return __builtin_bit_cast(bf16x8, v);
}

// ---------------------------------------------------------------------------
// Stage 0: convert X (key/value/query, each [128,512] f32) -> bf16, row-major
// [mat][m][k].  grid 192, block 256, one f32x4 per thread.
// ---------------------------------------------------------------------------
__global__ __launch_bounds__(256) void prep_x(
    const float* __restrict__ key, const float* __restrict__ value,
    const float* __restrict__ query, u16* __restrict__ Xb)
{
  int idx = blockIdx.x * 256 + threadIdx.x;      // 0..49151
  int mat = idx >> 14;                           // 16384 chunks per mat
  int off = (idx & 16383) * 4;
  const float* src = mat == 0 ? key : (mat == 1 ? value : query);
  f32x4 v = *(const f32x4*)(src + off);
  u16x4 o;
#pragma unroll
  for (int i = 0; i < 4; ++i) o[i] = __builtin_bit_cast(u16, (__bf16)v[i]);
  *(u16x4*)(Xb + mat * 65536 + off) = o;
}

// ---------------------------------------------------------------------------
// Stage 1: QKV projection, streaming (no LDS, no barriers).
// Xb[mat][128,512]bf16 @ W[512,65536]f32 + b -> bf16 out.
// grid (512, 3), block 256 (4 waves, 2x2 wave grid, 64x64 out per wave).
// A frags: direct 16B bf16 loads (L2-resident).  B frags: direct scalar f32
// loads in MFMA fragment shape, converted in-register.
// ---------------------------------------------------------------------------
__global__ __launch_bounds__(256, 2) void qkv_gemm(
    const u16* __restrict__ Xb,
    const float* __restrict__ Wk, const float* __restrict__ bk,
    const float* __restrict__ Wv, const float* __restrict__ bv,
    const float* __restrict__ Wq, const float* __restrict__ bq,
    u16* __restrict__ Kp, u16* __restrict__ Vp, u16* __restrict__ Qp)
{
  const int mat = blockIdx.y;
  const float* W    = mat == 0 ? Wk : (mat == 1 ? Wv : Wq);
  const float* bias = mat == 0 ? bk : (mat == 1 ? bv : bq);
  u16* out          = mat == 0 ? Kp : (mat == 1 ? Vp : Qp);
  const u16* Xm = Xb + mat * 65536;
  const int n0 = blockIdx.x * 128;

  const int t = threadIdx.x, lane = t & 63, wid = t >> 6;
  const int wm = wid >> 1, wn = wid & 1;
  const int l15 = lane & 15, lg = lane >> 4;
  const int col0 = n0 + wn * 64 + l15;

  f32x4 acc[4][4];
#pragma unroll
  for (int i = 0; i < 4; ++i)
#pragma unroll
    for (int j = 0; j < 4; ++j) acc[i][j] = (f32x4){0.f, 0.f, 0.f, 0.f};

#pragma unroll 2
  for (int ks = 0; ks < 16; ++ks) {
    const int krow = ks * 32 + lg * 8;
    // A fragments: [m][k0..k0+7] contiguous 16B each
    bf16x8 af[4];
#pragma unroll
    for (int mf = 0; mf < 4; ++mf)
      af[mf] = *(const bf16x8*)(Xm + (wm * 64 + mf * 16 + l15) * 512 + krow);
    // B fragments: lane (l15,lg) reads W[krow+j][col0 + nf*16]
    float bb[8][4];
#pragma unroll
    for (int j = 0; j < 8; ++j) {
      const float* Wr = W + (size_t)(krow + j) * 65536 + col0;
#pragma unroll
      for (int nf = 0; nf < 4; ++nf) bb[j][nf] = Wr[nf * 16];
    }
    bf16x8 bfr[4];
#pragma unroll
    for (int nf = 0; nf < 4; ++nf) {
      bf16x8 v;
#pragma unroll
      for (int j = 0; j < 8; ++j) v[j] = (__bf16)bb[j][nf];
      bfr[nf] = v;
    }
#pragma unroll
    for (int mf = 0; mf < 4; ++mf)
#pragma unroll
      for (int nf = 0; nf < 4; ++nf)
        acc[mf][nf] = __builtin_amdgcn_mfma_f32_16x16x32_bf16(af[mf], bfr[nf], acc[mf][nf], 0, 0, 0);
  }

  // epilogue: + bias, -> bf16
#pragma unroll
  for (int nf = 0; nf < 4; ++nf) {
    int col = wn * 64 + nf * 16 + l15;
    float bv_ = bias[n0 + col];
#pragma unroll
    for (int mf = 0; mf < 4; ++mf) {
      int row0 = wm * 64 + mf * 16 + lg * 4;
#pragma unroll
      for (int r = 0; r < 4; ++r) {
        out[(size_t)(row0 + r) * 65536 + n0 + col] = f2b(acc[mf][nf][r] + bv_);
      }
    }
  }
}

// ---------------------------------------------------------------------------
// Stage 2: attention per (b,h).  q,k,v [128,32] bf16.  grid 2048, block 256.
// ---------------------------------------------------------------------------
__global__ __launch_bounds__(256) void attn_kernel(
    const u16* __restrict__ Qp, const u16* __restrict__ Kp, const u16* __restrict__ Vp,
    float* __restrict__ attnOut, u16* __restrict__ ctx)
{
  const int bh = blockIdx.x;
  const int b = bh >> 4, h = bh & 15;
  const size_t base = (size_t)b * 65536 + h * 4096;

  __shared__ u16 qS[8 * 512];   // [kq_d][128 s][4]
  __shared__ u16 kS[8 * 512];   // [kq_d][128 j][4]
  __shared__ u16 vS[32 * 128];  // [kq_j][32 d][4]
  __shared__ u16 pS[32 * 512];  // [kq_j][128 i][4]

  const int t = threadIdx.x;
  const int lane = t & 63, w = t >> 6;
  const int l15 = lane & 15, lg = lane >> 4;

#pragma unroll
  for (int p = 0; p < 2; ++p) {
    int idx = p * 256 + t;
    int s = idx >> 2, dc = idx & 3;
    u16x8 qv = *(const u16x8*)(Qp + base + s * 32 + dc * 8);
    u16x8 kv = *(const u16x8*)(Kp + base + s * 32 + dc * 8);
    u16x8 vv = *(const u16x8*)(Vp + base + s * 32 + dc * 8);
    *(u16x4*)(qS + (dc * 2) * 512 + s * 4)     = __builtin_shufflevector(qv, qv, 0, 1, 2, 3);
    *(u16x4*)(qS + (dc * 2 + 1) * 512 + s * 4) = __builtin_shufflevector(qv, qv, 4, 5, 6, 7);
    *(u16x4*)(kS + (dc * 2) * 512 + s * 4)     = __builtin_shufflevector(kv, kv, 0, 1, 2, 3);
    *(u16x4*)(kS + (dc * 2 + 1) * 512 + s * 4) = __builtin_shufflevector(kv, kv, 4, 5, 6, 7);
#pragma unroll
    for (int i = 0; i < 8; ++i)
      vS[(s >> 2) * 128 + (dc * 8 + i) * 4 + (s & 3)] = vv[i];
  }
  __syncthreads();

  f32x4 sc[2][8];
#pragma unroll
  for (int i = 0; i < 2; ++i)
#pragma unroll
    for (int j = 0; j < 8; ++j) sc[i][j] = (f32x4){0.f, 0.f, 0.f, 0.f};

  {
    const int kqA = lg * 2;
    bf16x8 aq[2];
#pragma unroll
    for (int mf = 0; mf < 2; ++mf) {
      int m = w * 32 + mf * 16 + l15;
      u16x4 lo = *(const u16x4*)(qS + kqA * 512 + m * 4);
      u16x4 hi = *(const u16x4*)(qS + (kqA + 1) * 512 + m * 4);
      aq[mf] = mk8(lo, hi);
    }
#pragma unroll
    for (int nf = 0; nf < 8; ++nf) {
      int j = nf * 16 + l15;
      u16x4 lo = *(const u16x4*)(kS + kqA * 512 + j * 4);
      u16x4 hi = *(const u16x4*)(kS + (kqA + 1) * 512 + j * 4);
      bf16x8 bk8 = mk8(lo, hi);
#pragma unroll
      for (int mf = 0; mf < 2; ++mf)
        sc[mf][nf] = __builtin_amdgcn_mfma_f32_16x16x32_bf16(aq[mf], bk8, sc[mf][nf], 0, 0, 0);
    }
  }

  const float SCL = 0.70710678118654752f;
#pragma unroll
  for (int mf = 0; mf < 2; ++mf) {
#pragma unroll
    for (int r = 0; r < 4; ++r) {
      float m8 = -1e30f;
#pragma unroll
      for (int nf = 0; nf < 8; ++nf) m8 = fmaxf(m8, sc[mf][nf][r]);
      m8 = fmaxf(m8, __shfl_xor(m8, 1));
      m8 = fmaxf(m8, __shfl_xor(m8, 2));
      m8 = fmaxf(m8, __shfl_xor(m8, 4));
      m8 = fmaxf(m8, __shfl_xor(m8, 8));
      float s8 = 0.f;
#pragma unroll
      for (int nf = 0; nf < 8; ++nf) {
        float pv = __expf((sc[mf][nf][r] - m8) * SCL);
        sc[mf][nf][r] = pv;
        s8 += pv;
      }
      s8 += __shfl_xor(s8, 1);
      s8 += __shfl_xor(s8, 2);
      s8 += __shfl_xor(s8, 4);
      s8 += __shfl_xor(s8, 8);
      float inv = 1.0f / s8;
      int i = w * 32 + mf * 16 + lg * 4 + r;
      float* ao = attnOut + (size_t)bh * 16384 + (size_t)i * 128;
#pragma unroll
      for (int nf = 0; nf < 8; ++nf) {
        int j = nf * 16 + l15;
        float pv = sc[mf][nf][r] * inv;
        ao[j] = pv;
        pS[(j >> 2) * 512 + i * 4 + (j & 3)] = f2b(pv);
      }
    }
  }
  __syncthreads();

  f32x4 cacc[2][2];
#pragma unroll
  for (int i = 0; i < 2; ++i)
#pragma unroll
    for (int j = 0; j < 2; ++j) cacc[i][j] = (f32x4){0.f, 0.f, 0.f, 0.f};

#pragma unroll
  for (int ks2 = 0; ks2 < 4; ++ks2) {
    const int kqP = ks2 * 8 + lg * 2;
    bf16x8 ap[2];
#pragma unroll
    for (int mf = 0; mf < 2; ++mf) {
      int i = w * 32 + mf * 16 + l15;
      u16x4 lo = *(const u16x4*)(pS + kqP * 512 + i * 4);
      u16x4 hi = *(const u16x4*)(pS + (kqP + 1) * 512 + i * 4);
      ap[mf] = mk8(lo, hi);
    }
#pragma unroll
    for (int nf = 0; nf < 2; ++nf) {
      int d = nf * 16 + l15;
      u16x4 lo = *(const u16x4*)(vS + kqP * 128 + d * 4);
      u16x4 hi = *(const u16x4*)(vS + (kqP + 1) * 128 + d * 4);
      bf16x8 bv8 = mk8(lo, hi);
#pragma unroll
      for (int mf = 0; mf < 2; ++mf)
        cacc[mf][nf] = __builtin_amdgcn_mfma_f32_16x16x32_bf16(ap[mf], bv8, cacc[mf][nf], 0, 0, 0);
    }
  }

#pragma unroll
  for (int mf = 0; mf < 2; ++mf) {
#pragma unroll
    for (int r = 0; r < 4; ++r) {
      int s = w * 32 + mf * 16 + lg * 4 + r;
      size_t rowbase = ((size_t)b * 128 + h * 8 + (s >> 4)) * 512 + (s & 15) * 32;
#pragma unroll
      for (int nf = 0; nf < 2; ++nf) {
        int d = nf * 16 + l15;
        ctx[rowbase + d] = f2b(cacc[mf][nf][r]);
      }
    }
  }
}

// ---------------------------------------------------------------------------
// Stage 3a: out = ctx[16384,512]bf16 @ Wo[512,512]f32 + bo + residual -> f32 pre
// grid (128, 4), block 256.
// ---------------------------------------------------------------------------
__global__ __launch_bounds__(256) void out_proj(
    const u16* __restrict__ ctx, const float* __restrict__ Wo, const float* __restrict__ bo,
    const float* __restrict__ query, float* __restrict__ pre)
{
  const int m0 = blockIdx.x * 128;
  const int n0 = blockIdx.y * 128;

  __shared__ u16 As[16 * 512];
  __shared__ u16 Bs[16 * 512];

  const int t = threadIdx.x;
  const int lane = t & 63, wid = t >> 6;
  const int wm = wid >> 1, wn = wid & 1;
  const int l15 = lane & 15, lg = lane >> 4;

  f32x4 acc[4][4];
#pragma unroll
  for (int i = 0; i < 4; ++i)
#pragma unroll
    for (int j = 0; j < 4; ++j) acc[i][j] = (f32x4){0.f, 0.f, 0.f, 0.f};

  for (int it = 0; it < 8; ++it) {
    const int k0 = it * 64;
#pragma unroll
    for (int p = 0; p < 4; ++p) {
      int idx = p * 256 + t;
      int m = idx >> 3, dc = idx & 7;
      u16x8 av = *(const u16x8*)(ctx + (size_t)(m0 + m) * 512 + k0 + dc * 8);
      int kq = dc * 2;
      *(u16x4*)(As + kq * 512 + (((m + 2 * kq) & 127) << 2)) =
          __builtin_shufflevector(av, av, 0, 1, 2, 3);
      *(u16x4*)(As + (kq + 1) * 512 + (((m + 2 * (kq + 1)) & 127) << 2)) =
          __builtin_shufflevector(av, av, 4, 5, 6, 7);
    }
#pragma unroll
    for (int p = 0; p < 8; ++p) {
      int idx = p * 256 + t;
      int n = idx & 127, kq = idx >> 7;
      const float* wp = Wo + (size_t)(k0 + kq * 4) * 512 + n0 + n;
      u16x4 uv;
      uv[0] = f2b(wp[0]);
      uv[1] = f2b(wp[512]);
      uv[2] = f2b(wp[1024]);
      uv[3] = f2b(wp[1536]);
      *(u16x4*)(Bs + kq * 512 + n * 4) = uv;
    }
    __syncthreads();
#pragma unroll
    for (int kstep = 0; kstep < 2; ++kstep) {
      const int kqA = kstep * 8 + lg * 2;
      bf16x8 af[4], bfr[4];
#pragma unroll
      for (int mf = 0; mf < 4; ++mf) {
        int m = wm * 64 + mf * 16 + l15;
        u16x4 lo = *(const u16x4*)(As + kqA * 512 + (((m + 2 * kqA) & 127) << 2));
        u16x4 hi = *(const u16x4*)(As + (kqA + 1) * 512 + (((m + 2 * (kqA + 1)) & 127) << 2));
        af[mf] = mk8(lo, hi);
      }
#pragma unroll
      for (int nf = 0; nf < 4; ++nf) {
        int n = wn * 64 + nf * 16 + l15;
        u16x4 lo = *(const u16x4*)(Bs + kqA * 512 + n * 4);
        u16x4 hi = *(const u16x4*)(Bs + (kqA + 1) * 512 + n * 4);
        bfr[nf] = mk8(lo, hi);
      }
#pragma unroll
      for (int mf = 0; mf < 4; ++mf)
#pragma unroll
        for (int nf = 0; nf < 4; ++nf)
          acc[mf][nf] = __builtin_amdgcn_mfma_f32_16x16x32_bf16(af[mf], bfr[nf], acc[mf][nf], 0, 0, 0);
    }
    __syncthreads();
  }

#pragma unroll
  for (int nf = 0; nf < 4; ++nf) {
    int col = wn * 64 + nf * 16 + l15;
    float bv_ = bo[n0 + col];
#pragma unroll
    for (int mf = 0; mf < 4; ++mf) {
      int row0 = wm * 64 + mf * 16 + lg * 4;
#pragma unroll
      for (int r = 0; r < 4; ++r) {
        int m = m0 + row0 + r;
        float res = query[(m >> 7) * 512 + n0 + col];
        pre[(size_t)m * 512 + n0 + col] = acc[mf][nf][r] + bv_ + res;
      }
    }
  }
}

// ---------------------------------------------------------------------------
// Stage 3b: LayerNorm over last dim (512).  One wave per row. grid 4096, blk 256.
// ---------------------------------------------------------------------------
__global__ __launch_bounds__(256) void ln_kernel(
    const float* __restrict__ pre, const float* __restrict__ gamma,
    const float* __restrict__ beta, float* __restrict__ out0)
{
  const int w = threadIdx.x >> 6, lane = threadIdx.x & 63;
  const int row = blockIdx.x * 4 + w;
  const float* x = pre + (size_t)row * 512;
  f32x4 v0 = *(const f32x4*)(x + lane * 8);
  f32x4 v1 = *(const f32x4*)(x + lane * 8 + 4);
  float s = v0[0] + v0[1] + v0[2] + v0[3] + v1[0] + v1[1] + v1[2] + v1[3];
  float q = v0[0] * v0[0] + v0[1] * v0[1] + v0[2] * v0[2] + v0[3] * v0[3] +
            v1[0] * v1[0] + v1[1] * v1[1] + v1[2] * v1[2] + v1[3] * v1[3];
#pragma unroll
  for (int m = 1; m < 64; m <<= 1) {
    s += __shfl_xor(s, m);
    q += __shfl_xor(q, m);
  }
  float mean = s * (1.f / 512.f);
  float var = q * (1.f / 512.f) - mean * mean;
  float rs = rsqrtf(var + 1e-5f);
  f32x4 g0 = *(const f32x4*)(gamma + lane * 8);
  f32x4 g1 = *(const f32x4*)(gamma + lane * 8 + 4);
  f32x4 b0 = *(const f32x4*)(beta + lane * 8);
  f32x4 b1 = *(const f32x4*)(beta + lane * 8 + 4);
  f32x4 o0, o1;
#pragma unroll
  for (int i = 0; i < 4; ++i) {
    o0[i] = (v0[i] - mean) * rs * g0[i] + b0[i];
    o1[i] = (v1[i] - mean) * rs * g1[i] + b1[i];
  }
  *(f32x4*)(out0 + (size_t)row * 512 + lane * 8) = o0;
  *(f32x4*)(out0 + (size_t)row * 512 + lane * 8 + 4) = o1;
}

// ---------------------------------------------------------------------------
extern "C" void kernel_launch(void* const* d_in, const int* in_sizes, int n_in,
                              void* d_out, int out_size, void* d_ws, size_t ws_size,
                              hipStream_t stream) {
  (void)in_sizes; (void)n_in; (void)out_size; (void)ws_size;
  const float* key   = (const float*)d_in[0];
  const float* value = (const float*)d_in[1];
  const float* query = (const float*)d_in[2];
  const float* Wk    = (const float*)d_in[3];
  const float* bk    = (const float*)d_in[4];
  const float* Wv    = (const float*)d_in[5];
  const float* bv    = (const float*)d_in[6];
  const float* Wq    = (const float*)d_in[7];
  const float* bq    = (const float*)d_in[8];
  const float* Wo    = (const float*)d_in[9];
  const float* bo    = (const float*)d_in[10];
  const float* gamma = (const float*)d_in[11];
  const float* beta  = (const float*)d_in[12];

  char* ws = (char*)d_ws;
  u16* Kp  = (u16*)(ws + 0);               // 16 MB  (128 x 65536 bf16)
  u16* Vp  = (u16*)(ws + 16777216);        // 16 MB
  u16* Qp  = (u16*)(ws + 33554432);        // 16 MB
  u16* ctx = (u16*)(ws + 50331648);        // 16 MB  (16384 x 512 bf16)
  u16* Xb  = (u16*)(ws + 50331648);        // 384 KB, overlays ctx region (dead until attn)
  float* pre = (float*)(ws + 0);           // 32 MB, overlays dead K/V after attn

  float* out0    = (float*)d_out;          // [128,128,512] LN result
  float* attnOut = out0 + 8388608;         // [2048,128,128] attn

  prep_x<<<dim3(192), 256, 0, stream>>>(key, value, query, Xb);
  qkv_gemm<<<dim3(512, 3), 256, 0, stream>>>(Xb, Wk, bk, Wv, bv, Wq, bq, Kp, Vp, Qp);
  attn_kernel<<<dim3(2048), 256, 0, stream>>>(Qp, Kp, Vp, attnOut, ctx);
  out_proj<<<dim3(128, 4), 256, 0, stream>>>(ctx, Wo, bo, query, pre);
  ln_kernel<<<dim3(4096), 256, 0, stream>>>(pre, gamma, beta, out0);
}

// Round 3
// 198.636 us; speedup vs baseline: 1.1621x; 1.1621x over previous
//
#include <hip/hip_runtime.h>

typedef unsigned short u16;
typedef unsigned int u32;
typedef __attribute__((ext_vector_type(4))) float f32x4;
typedef __attribute__((ext_vector_type(4))) u16 u16x4;
typedef __attribute__((ext_vector_type(8))) u16 u16x8;
typedef __attribute__((ext_vector_type(8))) __bf16 bf16x8;

#define DEV static __device__ __forceinline__

DEV u16 f2b(float f) {
  u32 u = __builtin_bit_cast(u32, f);
  u32 r = (u + 0x7fffu + ((u >> 16) & 1u)) >> 16;
  return (u16)r;
}

DEV bf16x8 mk8(u16x4 lo, u16x4 hi) {
  u16x8 v = __builtin_shufflevector(lo, hi, 0, 1, 2, 3, 4, 5, 6, 7);
  return __builtin_bit_cast(bf16x8, v);
}

// ---------------------------------------------------------------------------
// Stage 0: convert X (key/value/query, each [128,512] f32) -> bf16 row-major.
// ---------------------------------------------------------------------------
__global__ __launch_bounds__(256) void prep_x(
    const float* __restrict__ key, const float* __restrict__ value,
    const float* __restrict__ query, u16* __restrict__ Xb)
{
  int idx = blockIdx.x * 256 + threadIdx.x;      // 0..49151
  int mat = idx >> 14;
  int off = (idx & 16383) * 4;
  const float* src = mat == 0 ? key : (mat == 1 ? value : query);
  f32x4 v = *(const f32x4*)(src + off);
  u16x4 o;
#pragma unroll
  for (int i = 0; i < 4; ++i) o[i] = __builtin_bit_cast(u16, (__bf16)v[i]);
  *(u16x4*)(Xb + mat * 65536 + off) = o;
}

// ---------------------------------------------------------------------------
// Stage 1: QKV projection.  Xb[mat][128,512]bf16 @ W[512,65536]f32 + b -> bf16.
// grid (256, 3), block 256.  BM=128 (all M), BN=256, BK=32.
// W staged f32 via global_load_lds width=16: one wave round = 1 KB contiguous
// (one full k-row slice) -> DRAM-page-friendly.  LDS linear [k][256] with a
// per-row rotation r(k)=4(k&7)+8(k>>3) applied on the GLOBAL source address
// (rule #21: linear dest + inverse-swizzled source + swizzled read).
// Double-buffered, raw s_barrier + uniform s_waitcnt vmcnt(4) (A(t)'s 4 loads
// are the only ops newer than stage(t) at the wait point).
// ---------------------------------------------------------------------------
DEV void stage_w(const float* __restrict__ W, int K0, int n0,
                 float* buf, int wv, int lane)
{
  // wave wv stages rows wv*8 + p (p=0..7); lane covers 16B of the 1KB row
#pragma unroll
  for (int p = 0; p < 8; ++p) {
    int kl = wv * 8 + p;                                   // 0..31
    int r = ((kl & 7) << 2) + (((kl >> 3) & 3) << 3);      // rotation
    int nphys = ((lane << 2) - r) & 255;
    const float* gp = W + (size_t)(K0 + kl) * 65536 + n0 + nphys;
    float* lp = buf + kl * 256;                            // wave-uniform base
    __builtin_amdgcn_global_load_lds(
        (const __attribute__((address_space(1))) u32*)gp,
        (__attribute__((address_space(3))) u32*)lp, 16, 0, 0);
  }
}

DEV void load_a(bf16x8* af, const u16* __restrict__ Xm, int kk,
                int wm, int l15, int lg)
{
#pragma unroll
  for (int mf = 0; mf < 4; ++mf)
    af[mf] = *(const bf16x8*)(Xm + (wm * 64 + mf * 16 + l15) * 512 + kk + lg * 8);
}

DEV void compute_tile(const float* __restrict__ B, const bf16x8* af,
                      f32x4 acc[4][8], int wn, int l15, int lg)
{
#pragma unroll
  for (int nf = 0; nf < 8; ++nf) {
    int bn0 = (wn * 128 + nf * 16 + l15 + 8 * lg) & 255;
    float f[8];
#pragma unroll
    for (int j = 0; j < 8; ++j)
      f[j] = B[(lg * 8 + j) * 256 + ((bn0 + 4 * j) & 255)];
    bf16x8 bv;
#pragma unroll
    for (int j = 0; j < 8; ++j) bv[j] = (__bf16)f[j];
#pragma unroll
    for (int mf = 0; mf < 4; ++mf)
      acc[mf][nf] = __builtin_amdgcn_mfma_f32_16x16x32_bf16(af[mf], bv, acc[mf][nf], 0, 0, 0);
  }
}

__global__ __launch_bounds__(256, 2) void qkv_gemm(
    const u16* __restrict__ Xb,
    const float* __restrict__ Wk, const float* __restrict__ bk,
    const float* __restrict__ Wv, const float* __restrict__ bv,
    const float* __restrict__ Wq, const float* __restrict__ bq,
    u16* __restrict__ Kp, u16* __restrict__ Vp, u16* __restrict__ Qp)
{
  const int mat = blockIdx.y;
  const float* W    = mat == 0 ? Wk : (mat == 1 ? Wv : Wq);
  const float* bias = mat == 0 ? bk : (mat == 1 ? bv : bq);
  u16* out          = mat == 0 ? Kp : (mat == 1 ? Vp : Qp);
  const u16* Xm = Xb + mat * 65536;
  const int n0 = blockIdx.x * 256;

  __shared__ float Bs0[32 * 256];   // 32 KB
  __shared__ float Bs1[32 * 256];   // 32 KB

  const int t = threadIdx.x, lane = t & 63, wv = t >> 6;
  const int wm = wv >> 1, wn = wv & 1;
  const int l15 = lane & 15, lg = lane >> 4;

  f32x4 acc[4][8];
#pragma unroll
  for (int i = 0; i < 4; ++i)
#pragma unroll
    for (int j = 0; j < 8; ++j) acc[i][j] = (f32x4){0.f, 0.f, 0.f, 0.f};

  bf16x8 af0[4], af1[4];

  // prologue: stage(0) then A(0) -> exactly 4 ops newer than stage(0)
  stage_w(W, 0, n0, Bs0, wv, lane);
  load_a(af0, Xm, 0, wm, l15, lg);

  for (int it = 0; it < 16; it += 2) {
    // ---- even body: consume Bs0/af0, stage Bs1/af1 ----
    asm volatile("s_waitcnt vmcnt(4)" ::: "memory");   // own stage(it) done
    asm volatile("s_barrier" ::: "memory");            // publish to block
    stage_w(W, (it + 1) * 32, n0, Bs1, wv, lane);
    load_a(af1, Xm, (it + 1) * 32, wm, l15, lg);
    compute_tile(Bs0, af0, acc, wn, l15, lg);

    // ---- odd body: consume Bs1/af1, stage Bs0/af0 ----
    asm volatile("s_waitcnt vmcnt(4)" ::: "memory");   // own stage(it+1) done
    asm volatile("s_barrier" ::: "memory");
    if (it + 2 < 16) {
      stage_w(W, (it + 2) * 32, n0, Bs0, wv, lane);
      load_a(af0, Xm, (it + 2) * 32, wm, l15, lg);
    }
    compute_tile(Bs1, af1, acc, wn, l15, lg);
  }

  // epilogue: + bias -> bf16
#pragma unroll
  for (int nf = 0; nf < 8; ++nf) {
    int col = wn * 128 + nf * 16 + l15;
    float bv_ = bias[n0 + col];
#pragma unroll
    for (int mf = 0; mf < 4; ++mf) {
      int row0 = wm * 64 + mf * 16 + lg * 4;
#pragma unroll
      for (int r = 0; r < 4; ++r) {
        out[(size_t)(row0 + r) * 65536 + n0 + col] = f2b(acc[mf][nf][r] + bv_);
      }
    }
  }
}

// ---------------------------------------------------------------------------
// Stage 2: attention per (b,h).  q,k,v [128,32] bf16.  grid 2048, block 256.
// ---------------------------------------------------------------------------
__global__ __launch_bounds__(256) void attn_kernel(
    const u16* __restrict__ Qp, const u16* __restrict__ Kp, const u16* __restrict__ Vp,
    float* __restrict__ attnOut, u16* __restrict__ ctx)
{
  const int bh = blockIdx.x;
  const int b = bh >> 4, h = bh & 15;
  const size_t base = (size_t)b * 65536 + h * 4096;

  __shared__ u16 qS[8 * 512];   // [kq_d][128 s][4]
  __shared__ u16 kS[8 * 512];
  __shared__ u16 vS[32 * 128];  // [kq_j][32 d][4]
  __shared__ u16 pS[32 * 512];  // [kq_j][128 i][4]

  const int t = threadIdx.x;
  const int lane = t & 63, w = t >> 6;
  const int l15 = lane & 15, lg = lane >> 4;

#pragma unroll
  for (int p = 0; p < 2; ++p) {
    int idx = p * 256 + t;
    int s = idx >> 2, dc = idx & 3;
    u16x8 qv = *(const u16x8*)(Qp + base + s * 32 + dc * 8);
    u16x8 kv = *(const u16x8*)(Kp + base + s * 32 + dc * 8);
    u16x8 vv = *(const u16x8*)(Vp + base + s * 32 + dc * 8);
    *(u16x4*)(qS + (dc * 2) * 512 + s * 4)     = __builtin_shufflevector(qv, qv, 0, 1, 2, 3);
    *(u16x4*)(qS + (dc * 2 + 1) * 512 + s * 4) = __builtin_shufflevector(qv, qv, 4, 5, 6, 7);
    *(u16x4*)(kS + (dc * 2) * 512 + s * 4)     = __builtin_shufflevector(kv, kv, 0, 1, 2, 3);
    *(u16x4*)(kS + (dc * 2 + 1) * 512 + s * 4) = __builtin_shufflevector(kv, kv, 4, 5, 6, 7);
#pragma unroll
    for (int i = 0; i < 8; ++i)
      vS[(s >> 2) * 128 + (dc * 8 + i) * 4 + (s & 3)] = vv[i];
  }
  __syncthreads();

  f32x4 sc[2][8];
#pragma unroll
  for (int i = 0; i < 2; ++i)
#pragma unroll
    for (int j = 0; j < 8; ++j) sc[i][j] = (f32x4){0.f, 0.f, 0.f, 0.f};

  {
    const int kqA = lg * 2;
    bf16x8 aq[2];
#pragma unroll
    for (int mf = 0; mf < 2; ++mf) {
      int m = w * 32 + mf * 16 + l15;
      u16x4 lo = *(const u16x4*)(qS + kqA * 512 + m * 4);
      u16x4 hi = *(const u16x4*)(qS + (kqA + 1) * 512 + m * 4);
      aq[mf] = mk8(lo, hi);
    }
#pragma unroll
    for (int nf = 0; nf < 8; ++nf) {
      int j = nf * 16 + l15;
      u16x4 lo = *(const u16x4*)(kS + kqA * 512 + j * 4);
      u16x4 hi = *(const u16x4*)(kS + (kqA + 1) * 512 + j * 4);
      bf16x8 bk8 = mk8(lo, hi);
#pragma unroll
      for (int mf = 0; mf < 2; ++mf)
        sc[mf][nf] = __builtin_amdgcn_mfma_f32_16x16x32_bf16(aq[mf], bk8, sc[mf][nf], 0, 0, 0);
    }
  }

  const float SCL = 0.70710678118654752f;
#pragma unroll
  for (int mf = 0; mf < 2; ++mf) {
#pragma unroll
    for (int r = 0; r < 4; ++r) {
      float m8 = -1e30f;
#pragma unroll
      for (int nf = 0; nf < 8; ++nf) m8 = fmaxf(m8, sc[mf][nf][r]);
      m8 = fmaxf(m8, __shfl_xor(m8, 1));
      m8 = fmaxf(m8, __shfl_xor(m8, 2));
      m8 = fmaxf(m8, __shfl_xor(m8, 4));
      m8 = fmaxf(m8, __shfl_xor(m8, 8));
      float s8 = 0.f;
#pragma unroll
      for (int nf = 0; nf < 8; ++nf) {
        float pv = __expf((sc[mf][nf][r] - m8) * SCL);
        sc[mf][nf][r] = pv;
        s8 += pv;
      }
      s8 += __shfl_xor(s8, 1);
      s8 += __shfl_xor(s8, 2);
      s8 += __shfl_xor(s8, 4);
      s8 += __shfl_xor(s8, 8);
      float inv = 1.0f / s8;
      int i = w * 32 + mf * 16 + lg * 4 + r;
      float* ao = attnOut + (size_t)bh * 16384 + (size_t)i * 128;
#pragma unroll
      for (int nf = 0; nf < 8; ++nf) {
        int j = nf * 16 + l15;
        float pv = sc[mf][nf][r] * inv;
        ao[j] = pv;
        pS[(j >> 2) * 512 + i * 4 + (j & 3)] = f2b(pv);
      }
    }
  }
  __syncthreads();

  f32x4 cacc[2][2];
#pragma unroll
  for (int i = 0; i < 2; ++i)
#pragma unroll
    for (int j = 0; j < 2; ++j) cacc[i][j] = (f32x4){0.f, 0.f, 0.f, 0.f};

#pragma unroll
  for (int ks2 = 0; ks2 < 4; ++ks2) {
    const int kqP = ks2 * 8 + lg * 2;
    bf16x8 ap[2];
#pragma unroll
    for (int mf = 0; mf < 2; ++mf) {
      int i = w * 32 + mf * 16 + l15;
      u16x4 lo = *(const u16x4*)(pS + kqP * 512 + i * 4);
      u16x4 hi = *(const u16x4*)(pS + (kqP + 1) * 512 + i * 4);
      ap[mf] = mk8(lo, hi);
    }
#pragma unroll
    for (int nf = 0; nf < 2; ++nf) {
      int d = nf * 16 + l15;
      u16x4 lo = *(const u16x4*)(vS + kqP * 128 + d * 4);
      u16x4 hi = *(const u16x4*)(vS + (kqP + 1) * 128 + d * 4);
      bf16x8 bv8 = mk8(lo, hi);
#pragma unroll
      for (int mf = 0; mf < 2; ++mf)
        cacc[mf][nf] = __builtin_amdgcn_mfma_f32_16x16x32_bf16(ap[mf], bv8, cacc[mf][nf], 0, 0, 0);
    }
  }

#pragma unroll
  for (int mf = 0; mf < 2; ++mf) {
#pragma unroll
    for (int r = 0; r < 4; ++r) {
      int s = w * 32 + mf * 16 + lg * 4 + r;
      size_t rowbase = ((size_t)b * 128 + h * 8 + (s >> 4)) * 512 + (s & 15) * 32;
#pragma unroll
      for (int nf = 0; nf < 2; ++nf) {
        int d = nf * 16 + l15;
        ctx[rowbase + d] = f2b(cacc[mf][nf][r]);
      }
    }
  }
}

// ---------------------------------------------------------------------------
// Stage 3a: out = ctx[16384,512]bf16 @ Wo[512,512]f32 + bo + residual -> f32 pre
// ---------------------------------------------------------------------------
__global__ __launch_bounds__(256) void out_proj(
    const u16* __restrict__ ctx, const float* __restrict__ Wo, const float* __restrict__ bo,
    const float* __restrict__ query, float* __restrict__ pre)
{
  const int m0 = blockIdx.x * 128;
  const int n0 = blockIdx.y * 128;

  __shared__ u16 As[16 * 512];
  __shared__ u16 Bs[16 * 512];

  const int t = threadIdx.x;
  const int lane = t & 63, wid = t >> 6;
  const int wm = wid >> 1, wn = wid & 1;
  const int l15 = lane & 15, lg = lane >> 4;

  f32x4 acc[4][4];
#pragma unroll
  for (int i = 0; i < 4; ++i)
#pragma unroll
    for (int j = 0; j < 4; ++j) acc[i][j] = (f32x4){0.f, 0.f, 0.f, 0.f};

  for (int it = 0; it < 8; ++it) {
    const int k0 = it * 64;
#pragma unroll
    for (int p = 0; p < 4; ++p) {
      int idx = p * 256 + t;
      int m = idx >> 3, dc = idx & 7;
      u16x8 av = *(const u16x8*)(ctx + (size_t)(m0 + m) * 512 + k0 + dc * 8);
      int kq = dc * 2;
      *(u16x4*)(As + kq * 512 + (((m + 2 * kq) & 127) << 2)) =
          __builtin_shufflevector(av, av, 0, 1, 2, 3);
      *(u16x4*)(As + (kq + 1) * 512 + (((m + 2 * (kq + 1)) & 127) << 2)) =
          __builtin_shufflevector(av, av, 4, 5, 6, 7);
    }
#pragma unroll
    for (int p = 0; p < 8; ++p) {
      int idx = p * 256 + t;
      int n = idx & 127, kq = idx >> 7;
      const float* wp = Wo + (size_t)(k0 + kq * 4) * 512 + n0 + n;
      u16x4 uv;
      uv[0] = f2b(wp[0]);
      uv[1] = f2b(wp[512]);
      uv[2] = f2b(wp[1024]);
      uv[3] = f2b(wp[1536]);
      *(u16x4*)(Bs + kq * 512 + n * 4) = uv;
    }
    __syncthreads();
#pragma unroll
    for (int kstep = 0; kstep < 2; ++kstep) {
      const int kqA = kstep * 8 + lg * 2;
      bf16x8 af[4], bfr[4];
#pragma unroll
      for (int mf = 0; mf < 4; ++mf) {
        int m = wm * 64 + mf * 16 + l15;
        u16x4 lo = *(const u16x4*)(As + kqA * 512 + (((m + 2 * kqA) & 127) << 2));
        u16x4 hi = *(const u16x4*)(As + (kqA + 1) * 512 + (((m + 2 * (kqA + 1)) & 127) << 2));
        af[mf] = mk8(lo, hi);
      }
#pragma unroll
      for (int nf = 0; nf < 4; ++nf) {
        int n = wn * 64 + nf * 16 + l15;
        u16x4 lo = *(const u16x4*)(Bs + kqA * 512 + n * 4);
        u16x4 hi = *(const u16x4*)(Bs + (kqA + 1) * 512 + n * 4);
        bfr[nf] = mk8(lo, hi);
      }
#pragma unroll
      for (int mf = 0; mf < 4; ++mf)
#pragma unroll
        for (int nf = 0; nf < 4; ++nf)
          acc[mf][nf] = __builtin_amdgcn_mfma_f32_16x16x32_bf16(af[mf], bfr[nf], acc[mf][nf], 0, 0, 0);
    }
    __syncthreads();
  }

#pragma unroll
  for (int nf = 0; nf < 4; ++nf) {
    int col = wn * 64 + nf * 16 + l15;
    float bv_ = bo[n0 + col];
#pragma unroll
    for (int mf = 0; mf < 4; ++mf) {
      int row0 = wm * 64 + mf * 16 + lg * 4;
#pragma unroll
      for (int r = 0; r < 4; ++r) {
        int m = m0 + row0 + r;
        float res = query[(m >> 7) * 512 + n0 + col];
        pre[(size_t)m * 512 + n0 + col] = acc[mf][nf][r] + bv_ + res;
      }
    }
  }
}

// ---------------------------------------------------------------------------
// Stage 3b: LayerNorm over last dim (512).  One wave per row.
// ---------------------------------------------------------------------------
__global__ __launch_bounds__(256) void ln_kernel(
    const float* __restrict__ pre, const float* __restrict__ gamma,
    const float* __restrict__ beta, float* __restrict__ out0)
{
  const int w = threadIdx.x >> 6, lane = threadIdx.x & 63;
  const int row = blockIdx.x * 4 + w;
  const float* x = pre + (size_t)row * 512;
  f32x4 v0 = *(const f32x4*)(x + lane * 8);
  f32x4 v1 = *(const f32x4*)(x + lane * 8 + 4);
  float s = v0[0] + v0[1] + v0[2] + v0[3] + v1[0] + v1[1] + v1[2] + v1[3];
  float q = v0[0] * v0[0] + v0[1] * v0[1] + v0[2] * v0[2] + v0[3] * v0[3] +
            v1[0] * v1[0] + v1[1] * v1[1] + v1[2] * v1[2] + v1[3] * v1[3];
#pragma unroll
  for (int m = 1; m < 64; m <<= 1) {
    s += __shfl_xor(s, m);
    q += __shfl_xor(q, m);
  }
  float mean = s * (1.f / 512.f);
  float var = q * (1.f / 512.f) - mean * mean;
  float rs = rsqrtf(var + 1e-5f);
  f32x4 g0 = *(const f32x4*)(gamma + lane * 8);
  f32x4 g1 = *(const f32x4*)(gamma + lane * 8 + 4);
  f32x4 b0 = *(const f32x4*)(beta + lane * 8);
  f32x4 b1 = *(const f32x4*)(beta + lane * 8 + 4);
  f32x4 o0, o1;
#pragma unroll
  for (int i = 0; i < 4; ++i) {
    o0[i] = (v0[i] - mean) * rs * g0[i] + b0[i];
    o1[i] = (v1[i] - mean) * rs * g1[i] + b1[i];
  }
  *(f32x4*)(out0 + (size_t)row * 512 + lane * 8) = o0;
  *(f32x4*)(out0 + (size_t)row * 512 + lane * 8 + 4) = o1;
}

// ---------------------------------------------------------------------------
extern "C" void kernel_launch(void* const* d_in, const int* in_sizes, int n_in,
                              void* d_out, int out_size, void* d_ws, size_t ws_size,
                              hipStream_t stream) {
  (void)in_sizes; (void)n_in; (void)out_size; (void)ws_size;
  const float* key   = (const float*)d_in[0];
  const float* value = (const float*)d_in[1];
  const float* query = (const float*)d_in[2];
  const float* Wk    = (const float*)d_in[3];
  const float* bk    = (const float*)d_in[4];
  const float* Wv    = (const float*)d_in[5];
  const float* bv    = (const float*)d_in[6];
  const float* Wq    = (const float*)d_in[7];
  const float* bq    = (const float*)d_in[8];
  const float* Wo    = (const float*)d_in[9];
  const float* bo    = (const float*)d_in[10];
  const float* gamma = (const float*)d_in[11];
  const float* beta  = (const float*)d_in[12];

  char* ws = (char*)d_ws;
  u16* Kp  = (u16*)(ws + 0);               // 16 MB  (128 x 65536 bf16)
  u16* Vp  = (u16*)(ws + 16777216);        // 16 MB
  u16* Qp  = (u16*)(ws + 33554432);        // 16 MB
  u16* ctx = (u16*)(ws + 50331648);        // 16 MB  (16384 x 512 bf16)
  u16* Xb  = (u16*)(ws + 50331648);        // 384 KB, overlays ctx (dead until attn)
  float* pre = (float*)(ws + 0);           // 32 MB, overlays dead K/V after attn

  float* out0    = (float*)d_out;          // [128,128,512] LN result
  float* attnOut = out0 + 8388608;         // [2048,128,128] attn

  prep_x<<<dim3(192), 256, 0, stream>>>(key, value, query, Xb);
  qkv_gemm<<<dim3(256, 3), 256, 0, stream>>>(Xb, Wk, bk, Wv, bv, Wq, bq, Kp, Vp, Qp);
  attn_kernel<<<dim3(2048), 256, 0, stream>>>(Qp, Kp, Vp, attnOut, ctx);
  out_proj<<<dim3(128, 4), 256, 0, stream>>>(ctx, Wo, bo, query, pre);
  ln_kernel<<<dim3(4096), 256, 0, stream>>>(pre, gamma, beta, out0);
}

// Round 4
// 189.781 us; speedup vs baseline: 1.2163x; 1.0467x over previous
//
#include <hip/hip_runtime.h>

typedef unsigned short u16;
typedef unsigned int u32;
typedef __attribute__((ext_vector_type(4))) float f32x4;
typedef __attribute__((ext_vector_type(4))) u16 u16x4;
typedef __attribute__((ext_vector_type(8))) u16 u16x8;
typedef __attribute__((ext_vector_type(8))) __bf16 bf16x8;

#define DEV static __device__ __forceinline__

DEV u16 f2b(float f) {
  u32 u = __builtin_bit_cast(u32, f);
  u32 r = (u + 0x7fffu + ((u >> 16) & 1u)) >> 16;
  return (u16)r;
}

DEV bf16x8 mk8(u16x4 lo, u16x4 hi) {
  u16x8 v = __builtin_shufflevector(lo, hi, 0, 1, 2, 3, 4, 5, 6, 7);
  return __builtin_bit_cast(bf16x8, v);
}

// ---------------------------------------------------------------------------
// Stage 0: convert X (key/value/query, each [128,512] f32) -> bf16 row-major.
// ---------------------------------------------------------------------------
__global__ __launch_bounds__(256) void prep_x(
    const float* __restrict__ key, const float* __restrict__ value,
    const float* __restrict__ query, u16* __restrict__ Xb)
{
  int idx = blockIdx.x * 256 + threadIdx.x;      // 0..49151
  int mat = idx >> 14;
  int off = (idx & 16383) * 4;
  const float* src = mat == 0 ? key : (mat == 1 ? value : query);
  f32x4 v = *(const f32x4*)(src + off);
  u16x4 o;
#pragma unroll
  for (int i = 0; i < 4; ++i) o[i] = __builtin_bit_cast(u16, (__bf16)v[i]);
  *(u16x4*)(Xb + mat * 65536 + off) = o;
}

// ---------------------------------------------------------------------------
// Stage 1: QKV projection.  Xb[mat][128,512]bf16 @ W[512,65536]f32 + b -> bf16.
// grid 1536 (512 n-blocks x 3 mats merged -> exactly 3 resident generations),
// block 256 (4 waves, 2x2, 64x64 out each).  BM=128, BN=128, BK=32.
// Triple-buffered, 2-tiles-ahead pipeline: ALL loop loads are hand-issued
// global_load_lds (6 DMA/wave/iter) so vmcnt counts are exact; the counted
// s_waitcnt vmcnt(6) waits on loads issued TWO compute phases earlier.
// B LDS [k][128]f32 linear with k-dependent 16-float rotation applied on the
// DMA *source* (rule #21) -> frag reads are exact 2-way bank (free).
// A LDS [m][32]bf16 linear; frag read = ds_read_b128, uniform banks.
// ---------------------------------------------------------------------------
DEV void stage_b(const float* __restrict__ W, int k0, int n0,
                 float* buf, int wv, int lane)
{
#pragma unroll
  for (int p = 0; p < 4; ++p) {
    int q = wv * 4 + p;                      // 0..15, 1 KB per DMA
    int kl = q * 2 + (lane >> 5);            // local k row 0..31
    int rot = ((kl >> 3) & 1) << 4;          // 16-float rotation
    int nphys = (((lane & 31) << 2) - rot) & 127;
    const float* gp = W + (size_t)(k0 + kl) * 65536 + n0 + nphys;
    float* lp = buf + q * 256;               // wave-uniform dest base
    __builtin_amdgcn_global_load_lds(
        (const __attribute__((address_space(1))) u32*)gp,
        (__attribute__((address_space(3))) u32*)lp, 16, 0, 0);
  }
}

DEV void stage_a(const u16* __restrict__ Xm, int k0,
                 u16* buf, int wv, int lane)
{
#pragma unroll
  for (int p = 0; p < 2; ++p) {
    int q = wv * 2 + p;                      // 0..7, 1 KB per DMA
    int m = q * 16 + (lane >> 2);
    const u16* gp = Xm + m * 512 + k0 + (lane & 3) * 8;
    u16* lp = buf + q * 512;                 // wave-uniform dest base
    __builtin_amdgcn_global_load_lds(
        (const __attribute__((address_space(1))) u32*)gp,
        (__attribute__((address_space(3))) u32*)lp, 16, 0, 0);
  }
}

DEV void qkv_compute(const u16* __restrict__ A, const float* __restrict__ B,
                     f32x4 acc[4][4], int wm, int wn, int l15, int lg)
{
  bf16x8 af[4];
#pragma unroll
  for (int mf = 0; mf < 4; ++mf)
    af[mf] = *(const bf16x8*)(A + (wm * 64 + mf * 16 + l15) * 32 + lg * 8);
  const int rot = (lg & 1) << 4;
#pragma unroll
  for (int nf = 0; nf < 4; ++nf) {
    const int ncol = (wn * 64 + nf * 16 + l15 + rot) & 127;
    bf16x8 bv;
#pragma unroll
    for (int j = 0; j < 8; ++j)
      bv[j] = (__bf16)B[(lg * 8 + j) * 128 + ncol];
#pragma unroll
    for (int mf = 0; mf < 4; ++mf)
      acc[mf][nf] = __builtin_amdgcn_mfma_f32_16x16x32_bf16(af[mf], bv, acc[mf][nf], 0, 0, 0);
  }
}

__global__ __launch_bounds__(256, 2) void qkv_gemm(
    const u16* __restrict__ Xb,
    const float* __restrict__ Wk, const float* __restrict__ bk,
    const float* __restrict__ Wv, const float* __restrict__ bv,
    const float* __restrict__ Wq, const float* __restrict__ bq,
    u16* __restrict__ Kp, u16* __restrict__ Vp, u16* __restrict__ Qp)
{
  const int bx = blockIdx.x;
  const int mat = bx >> 9;                   // 512 n-blocks per mat
  const float* W    = mat == 0 ? Wk : (mat == 1 ? Wv : Wq);
  const float* bias = mat == 0 ? bk : (mat == 1 ? bv : bq);
  u16* out          = mat == 0 ? Kp : (mat == 1 ? Vp : Qp);
  const u16* Xm = Xb + mat * 65536;
  const int n0 = (bx & 511) * 128;

  __shared__ float Bs[3][32 * 128];          // 3 x 16 KB
  __shared__ u16   As[3][128 * 32];          // 3 x 8 KB

  const int t = threadIdx.x, lane = t & 63, wv = t >> 6;
  const int wm = wv >> 1, wn = wv & 1;
  const int l15 = lane & 15, lg = lane >> 4;

  f32x4 acc[4][4];
#pragma unroll
  for (int i = 0; i < 4; ++i)
#pragma unroll
    for (int j = 0; j < 4; ++j) acc[i][j] = (f32x4){0.f, 0.f, 0.f, 0.f};

  // prologue: 2 tiles in flight (12 DMAs/wave)
  stage_b(W,  0, n0, &Bs[0][0], wv, lane);
  stage_a(Xm, 0,     &As[0][0], wv, lane);
  stage_b(W, 32, n0, &Bs[1][0], wv, lane);
  stage_a(Xm, 32,    &As[1][0], wv, lane);

#define QKV_ITER(T, WAITS, ISSUE)                                         \
  {                                                                       \
    asm volatile("s_waitcnt vmcnt(" WAITS ")" ::: "memory");              \
    __builtin_amdgcn_sched_barrier(0);                                    \
    __builtin_amdgcn_s_barrier();                                         \
    __builtin_amdgcn_sched_barrier(0);                                    \
    if (ISSUE) {                                                          \
      stage_b(W,  ((T) + 2) * 32, n0, &Bs[((T) + 2) % 3][0], wv, lane);   \
      stage_a(Xm, ((T) + 2) * 32,     &As[((T) + 2) % 3][0], wv, lane);   \
    }                                                                     \
    qkv_compute(&As[(T) % 3][0], &Bs[(T) % 3][0], acc, wm, wn, l15, lg);  \
    __builtin_amdgcn_s_barrier();                                         \
  }

  QKV_ITER(0,  "6", 1)  QKV_ITER(1,  "6", 1)  QKV_ITER(2,  "6", 1)
  QKV_ITER(3,  "6", 1)  QKV_ITER(4,  "6", 1)  QKV_ITER(5,  "6", 1)
  QKV_ITER(6,  "6", 1)  QKV_ITER(7,  "6", 1)  QKV_ITER(8,  "6", 1)
  QKV_ITER(9,  "6", 1)  QKV_ITER(10, "6", 1)  QKV_ITER(11, "6", 1)
  QKV_ITER(12, "6", 1)  QKV_ITER(13, "6", 1)
  QKV_ITER(14, "6", 0)                        // queue: [14:6][15:6]
  QKV_ITER(15, "0", 0)                        // queue: [15:6] -> drain
#undef QKV_ITER

  // epilogue: + bias -> bf16
#pragma unroll
  for (int nf = 0; nf < 4; ++nf) {
    int col = wn * 64 + nf * 16 + l15;
    float bv_ = bias[n0 + col];
#pragma unroll
    for (int mf = 0; mf < 4; ++mf) {
      int row0 = wm * 64 + mf * 16 + lg * 4;
#pragma unroll
      for (int r = 0; r < 4; ++r) {
        out[(size_t)(row0 + r) * 65536 + n0 + col] = f2b(acc[mf][nf][r] + bv_);
      }
    }
  }
}

// ---------------------------------------------------------------------------
// Stage 2: attention per (b,h).  q,k,v [128,32] bf16.  grid 2048, block 256.
// ---------------------------------------------------------------------------
__global__ __launch_bounds__(256) void attn_kernel(
    const u16* __restrict__ Qp, const u16* __restrict__ Kp, const u16* __restrict__ Vp,
    float* __restrict__ attnOut, u16* __restrict__ ctx)
{
  const int bh = blockIdx.x;
  const int b = bh >> 4, h = bh & 15;
  const size_t base = (size_t)b * 65536 + h * 4096;

  __shared__ u16 qS[8 * 512];   // [kq_d][128 s][4]
  __shared__ u16 kS[8 * 512];
  __shared__ u16 vS[32 * 128];  // [kq_j][32 d][4]
  __shared__ u16 pS[32 * 512];  // [kq_j][128 i][4]

  const int t = threadIdx.x;
  const int lane = t & 63, w = t >> 6;
  const int l15 = lane & 15, lg = lane >> 4;

#pragma unroll
  for (int p = 0; p < 2; ++p) {
    int idx = p * 256 + t;
    int s = idx >> 2, dc = idx & 3;
    u16x8 qv = *(const u16x8*)(Qp + base + s * 32 + dc * 8);
    u16x8 kv = *(const u16x8*)(Kp + base + s * 32 + dc * 8);
    u16x8 vv = *(const u16x8*)(Vp + base + s * 32 + dc * 8);
    *(u16x4*)(qS + (dc * 2) * 512 + s * 4)     = __builtin_shufflevector(qv, qv, 0, 1, 2, 3);
    *(u16x4*)(qS + (dc * 2 + 1) * 512 + s * 4) = __builtin_shufflevector(qv, qv, 4, 5, 6, 7);
    *(u16x4*)(kS + (dc * 2) * 512 + s * 4)     = __builtin_shufflevector(kv, kv, 0, 1, 2, 3);
    *(u16x4*)(kS + (dc * 2 + 1) * 512 + s * 4) = __builtin_shufflevector(kv, kv, 4, 5, 6, 7);
#pragma unroll
    for (int i = 0; i < 8; ++i)
      vS[(s >> 2) * 128 + (dc * 8 + i) * 4 + (s & 3)] = vv[i];
  }
  __syncthreads();

  f32x4 sc[2][8];
#pragma unroll
  for (int i = 0; i < 2; ++i)
#pragma unroll
    for (int j = 0; j < 8; ++j) sc[i][j] = (f32x4){0.f, 0.f, 0.f, 0.f};

  {
    const int kqA = lg * 2;
    bf16x8 aq[2];
#pragma unroll
    for (int mf = 0; mf < 2; ++mf) {
      int m = w * 32 + mf * 16 + l15;
      u16x4 lo = *(const u16x4*)(qS + kqA * 512 + m * 4);
      u16x4 hi = *(const u16x4*)(qS + (kqA + 1) * 512 + m * 4);
      aq[mf] = mk8(lo, hi);
    }
#pragma unroll
    for (int nf = 0; nf < 8; ++nf) {
      int j = nf * 16 + l15;
      u16x4 lo = *(const u16x4*)(kS + kqA * 512 + j * 4);
      u16x4 hi = *(const u16x4*)(kS + (kqA + 1) * 512 + j * 4);
      bf16x8 bk8 = mk8(lo, hi);
#pragma unroll
      for (int mf = 0; mf < 2; ++mf)
        sc[mf][nf] = __builtin_amdgcn_mfma_f32_16x16x32_bf16(aq[mf], bk8, sc[mf][nf], 0, 0, 0);
    }
  }

  const float SCL = 0.70710678118654752f;
#pragma unroll
  for (int mf = 0; mf < 2; ++mf) {
#pragma unroll
    for (int r = 0; r < 4; ++r) {
      float m8 = -1e30f;
#pragma unroll
      for (int nf = 0; nf < 8; ++nf) m8 = fmaxf(m8, sc[mf][nf][r]);
      m8 = fmaxf(m8, __shfl_xor(m8, 1));
      m8 = fmaxf(m8, __shfl_xor(m8, 2));
      m8 = fmaxf(m8, __shfl_xor(m8, 4));
      m8 = fmaxf(m8, __shfl_xor(m8, 8));
      float s8 = 0.f;
#pragma unroll
      for (int nf = 0; nf < 8; ++nf) {
        float pv = __expf((sc[mf][nf][r] - m8) * SCL);
        sc[mf][nf][r] = pv;
        s8 += pv;
      }
      s8 += __shfl_xor(s8, 1);
      s8 += __shfl_xor(s8, 2);
      s8 += __shfl_xor(s8, 4);
      s8 += __shfl_xor(s8, 8);
      float inv = 1.0f / s8;
      int i = w * 32 + mf * 16 + lg * 4 + r;
      float* ao = attnOut + (size_t)bh * 16384 + (size_t)i * 128;
#pragma unroll
      for (int nf = 0; nf < 8; ++nf) {
        int j = nf * 16 + l15;
        float pv = sc[mf][nf][r] * inv;
        ao[j] = pv;
        pS[(j >> 2) * 512 + i * 4 + (j & 3)] = f2b(pv);
      }
    }
  }
  __syncthreads();

  f32x4 cacc[2][2];
#pragma unroll
  for (int i = 0; i < 2; ++i)
#pragma unroll
    for (int j = 0; j < 2; ++j) cacc[i][j] = (f32x4){0.f, 0.f, 0.f, 0.f};

#pragma unroll
  for (int ks2 = 0; ks2 < 4; ++ks2) {
    const int kqP = ks2 * 8 + lg * 2;
    bf16x8 ap[2];
#pragma unroll
    for (int mf = 0; mf < 2; ++mf) {
      int i = w * 32 + mf * 16 + l15;
      u16x4 lo = *(const u16x4*)(pS + kqP * 512 + i * 4);
      u16x4 hi = *(const u16x4*)(pS + (kqP + 1) * 512 + i * 4);
      ap[mf] = mk8(lo, hi);
    }
#pragma unroll
    for (int nf = 0; nf < 2; ++nf) {
      int d = nf * 16 + l15;
      u16x4 lo = *(const u16x4*)(vS + kqP * 128 + d * 4);
      u16x4 hi = *(const u16x4*)(vS + (kqP + 1) * 128 + d * 4);
      bf16x8 bv8 = mk8(lo, hi);
#pragma unroll
      for (int mf = 0; mf < 2; ++mf)
        cacc[mf][nf] = __builtin_amdgcn_mfma_f32_16x16x32_bf16(ap[mf], bv8, cacc[mf][nf], 0, 0, 0);
    }
  }

#pragma unroll
  for (int mf = 0; mf < 2; ++mf) {
#pragma unroll
    for (int r = 0; r < 4; ++r) {
      int s = w * 32 + mf * 16 + lg * 4 + r;
      size_t rowbase = ((size_t)b * 128 + h * 8 + (s >> 4)) * 512 + (s & 15) * 32;
#pragma unroll
      for (int nf = 0; nf < 2; ++nf) {
        int d = nf * 16 + l15;
        ctx[rowbase + d] = f2b(cacc[mf][nf][r]);
      }
    }
  }
}

// ---------------------------------------------------------------------------
// Stage 3a: out = ctx[16384,512]bf16 @ Wo[512,512]f32 + bo + residual -> f32 pre
// ---------------------------------------------------------------------------
__global__ __launch_bounds__(256) void out_proj(
    const u16* __restrict__ ctx, const float* __restrict__ Wo, const float* __restrict__ bo,
    const float* __restrict__ query, float* __restrict__ pre)
{
  const int m0 = blockIdx.x * 128;
  const int n0 = blockIdx.y * 128;

  __shared__ u16 As[16 * 512];
  __shared__ u16 Bs[16 * 512];

  const int t = threadIdx.x;
  const int lane = t & 63, wid = t >> 6;
  const int wm = wid >> 1, wn = wid & 1;
  const int l15 = lane & 15, lg = lane >> 4;

  f32x4 acc[4][4];
#pragma unroll
  for (int i = 0; i < 4; ++i)
#pragma unroll
    for (int j = 0; j < 4; ++j) acc[i][j] = (f32x4){0.f, 0.f, 0.f, 0.f};

  for (int it = 0; it < 8; ++it) {
    const int k0 = it * 64;
#pragma unroll
    for (int p = 0; p < 4; ++p) {
      int idx = p * 256 + t;
      int m = idx >> 3, dc = idx & 7;
      u16x8 av = *(const u16x8*)(ctx + (size_t)(m0 + m) * 512 + k0 + dc * 8);
      int kq = dc * 2;
      *(u16x4*)(As + kq * 512 + (((m + 2 * kq) & 127) << 2)) =
          __builtin_shufflevector(av, av, 0, 1, 2, 3);
      *(u16x4*)(As + (kq + 1) * 512 + (((m + 2 * (kq + 1)) & 127) << 2)) =
          __builtin_shufflevector(av, av, 4, 5, 6, 7);
    }
#pragma unroll
    for (int p = 0; p < 8; ++p) {
      int idx = p * 256 + t;
      int n = idx & 127, kq = idx >> 7;
      const float* wp = Wo + (size_t)(k0 + kq * 4) * 512 + n0 + n;
      u16x4 uv;
      uv[0] = f2b(wp[0]);
      uv[1] = f2b(wp[512]);
      uv[2] = f2b(wp[1024]);
      uv[3] = f2b(wp[1536]);
      *(u16x4*)(Bs + kq * 512 + n * 4) = uv;
    }
    __syncthreads();
#pragma unroll
    for (int kstep = 0; kstep < 2; ++kstep) {
      const int kqA = kstep * 8 + lg * 2;
      bf16x8 af[4], bfr[4];
#pragma unroll
      for (int mf = 0; mf < 4; ++mf) {
        int m = wm * 64 + mf * 16 + l15;
        u16x4 lo = *(const u16x4*)(As + kqA * 512 + (((m + 2 * kqA) & 127) << 2));
        u16x4 hi = *(const u16x4*)(As + (kqA + 1) * 512 + (((m + 2 * (kqA + 1)) & 127) << 2));
        af[mf] = mk8(lo, hi);
      }
#pragma unroll
      for (int nf = 0; nf < 4; ++nf) {
        int n = wn * 64 + nf * 16 + l15;
        u16x4 lo = *(const u16x4*)(Bs + kqA * 512 + n * 4);
        u16x4 hi = *(const u16x4*)(Bs + (kqA + 1) * 512 + n * 4);
        bfr[nf] = mk8(lo, hi);
      }
#pragma unroll
      for (int mf = 0; mf < 4; ++mf)
#pragma unroll
        for (int nf = 0; nf < 4; ++nf)
          acc[mf][nf] = __builtin_amdgcn_mfma_f32_16x16x32_bf16(af[mf], bfr[nf], acc[mf][nf], 0, 0, 0);
    }
    __syncthreads();
  }

#pragma unroll
  for (int nf = 0; nf < 4; ++nf) {
    int col = wn * 64 + nf * 16 + l15;
    float bv_ = bo[n0 + col];
#pragma unroll
    for (int mf = 0; mf < 4; ++mf) {
      int row0 = wm * 64 + mf * 16 + lg * 4;
#pragma unroll
      for (int r = 0; r < 4; ++r) {
        int m = m0 + row0 + r;
        float res = query[(m >> 7) * 512 + n0 + col];
        pre[(size_t)m * 512 + n0 + col] = acc[mf][nf][r] + bv_ + res;
      }
    }
  }
}

// ---------------------------------------------------------------------------
// Stage 3b: LayerNorm over last dim (512).  One wave per row.
// ---------------------------------------------------------------------------
__global__ __launch_bounds__(256) void ln_kernel(
    const float* __restrict__ pre, const float* __restrict__ gamma,
    const float* __restrict__ beta, float* __restrict__ out0)
{
  const int w = threadIdx.x >> 6, lane = threadIdx.x & 63;
  const int row = blockIdx.x * 4 + w;
  const float* x = pre + (size_t)row * 512;
  f32x4 v0 = *(const f32x4*)(x + lane * 8);
  f32x4 v1 = *(const f32x4*)(x + lane * 8 + 4);
  float s = v0[0] + v0[1] + v0[2] + v0[3] + v1[0] + v1[1] + v1[2] + v1[3];
  float q = v0[0] * v0[0] + v0[1] * v0[1] + v0[2] * v0[2] + v0[3] * v0[3] +
            v1[0] * v1[0] + v1[1] * v1[1] + v1[2] * v1[2] + v1[3] * v1[3];
#pragma unroll
  for (int m = 1; m < 64; m <<= 1) {
    s += __shfl_xor(s, m);
    q += __shfl_xor(q, m);
  }
  float mean = s * (1.f / 512.f);
  float var = q * (1.f / 512.f) - mean * mean;
  float rs = rsqrtf(var + 1e-5f);
  f32x4 g0 = *(const f32x4*)(gamma + lane * 8);
  f32x4 g1 = *(const f32x4*)(gamma + lane * 8 + 4);
  f32x4 b0 = *(const f32x4*)(beta + lane * 8);
  f32x4 b1 = *(const f32x4*)(beta + lane * 8 + 4);
  f32x4 o0, o1;
#pragma unroll
  for (int i = 0; i < 4; ++i) {
    o0[i] = (v0[i] - mean) * rs * g0[i] + b0[i];
    o1[i] = (v1[i] - mean) * rs * g1[i] + b1[i];
  }
  *(f32x4*)(out0 + (size_t)row * 512 + lane * 8) = o0;
  *(f32x4*)(out0 + (size_t)row * 512 + lane * 8 + 4) = o1;
}

// ---------------------------------------------------------------------------
extern "C" void kernel_launch(void* const* d_in, const int* in_sizes, int n_in,
                              void* d_out, int out_size, void* d_ws, size_t ws_size,
                              hipStream_t stream) {
  (void)in_sizes; (void)n_in; (void)out_size; (void)ws_size;
  const float* key   = (const float*)d_in[0];
  const float* value = (const float*)d_in[1];
  const float* query = (const float*)d_in[2];
  const float* Wk    = (const float*)d_in[3];
  const float* bk    = (const float*)d_in[4];
  const float* Wv    = (const float*)d_in[5];
  const float* bv    = (const float*)d_in[6];
  const float* Wq    = (const float*)d_in[7];
  const float* bq    = (const float*)d_in[8];
  const float* Wo    = (const float*)d_in[9];
  const float* bo    = (const float*)d_in[10];
  const float* gamma = (const float*)d_in[11];
  const float* beta  = (const float*)d_in[12];

  char* ws = (char*)d_ws;
  u16* Kp  = (u16*)(ws + 0);               // 16 MB  (128 x 65536 bf16)
  u16* Vp  = (u16*)(ws + 16777216);        // 16 MB
  u16* Qp  = (u16*)(ws + 33554432);        // 16 MB
  u16* ctx = (u16*)(ws + 50331648);        // 16 MB  (16384 x 512 bf16)
  u16* Xb  = (u16*)(ws + 50331648);        // 384 KB, overlays ctx (dead until attn)
  float* pre = (float*)(ws + 0);           // 32 MB, overlays dead K/V after attn

  float* out0    = (float*)d_out;          // [128,128,512] LN result
  float* attnOut = out0 + 8388608;         // [2048,128,128] attn

  prep_x<<<dim3(192), 256, 0, stream>>>(key, value, query, Xb);
  qkv_gemm<<<dim3(1536), 256, 0, stream>>>(Xb, Wk, bk, Wv, bv, Wq, bq, Kp, Vp, Qp);
  attn_kernel<<<dim3(2048), 256, 0, stream>>>(Qp, Kp, Vp, attnOut, ctx);
  out_proj<<<dim3(128, 4), 256, 0, stream>>>(ctx, Wo, bo, query, pre);
  ln_kernel<<<dim3(4096), 256, 0, stream>>>(pre, gamma, beta, out0);
}